// Round 11
// baseline (119.378 us; speedup 1.0000x reference)
//
#include <hip/hip_runtime.h>
#include <hip/hip_fp16.h>
#include <math.h>

// WayfinderAttention: B=1, H=16, T=2048, DH=64, D=64 neighbors. f32 in/out.
// R11: R10 (passed, absmax 0.015625, total 111.9us) + SINGLE DELTA:
//      V-row loads hoisted above score-compute/softmax (addresses depend only
//      on compacted indices) -> up to 24 gathers in flight per wave; V latency
//      overlaps the whole score+softmax phase. PV FMA order unchanged ->
//      numerics bit-identical to R10.
// Fallback to the proven R3 f32 kernel if ws_size < 8 MB.

#define T_DIM 2048
#define DH    64
#define NB    64
#define WPB   4
#define KV_ELEMS (16 * T_DIM * DH)   // 2,097,152 per tensor

typedef _Float16 h2_t __attribute__((ext_vector_type(2)));

// ---------------- prepass: f32 -> f16 (RTN), K then V ----------------
__global__ __launch_bounds__(256)
void convert_kv_kernel(const float* __restrict__ k, const float* __restrict__ v,
                       unsigned int* __restrict__ ws)
{
    const int tid = blockIdx.x * 256 + threadIdx.x;     // [0, KV_ELEMS/4)
    unsigned int* kh = ws;
    unsigned int* vh = ws + (KV_ELEMS / 2);
    const float4 kv = *(const float4*)(k + (long long)tid * 4);
    const float4 vv = *(const float4*)(v + (long long)tid * 4);
    h2_t k0 = { (_Float16)kv.x, (_Float16)kv.y };
    h2_t k1 = { (_Float16)kv.z, (_Float16)kv.w };
    h2_t v0 = { (_Float16)vv.x, (_Float16)vv.y };
    h2_t v1 = { (_Float16)vv.z, (_Float16)vv.w };
    uint2 pk, pv;
    pk.x = __builtin_bit_cast(unsigned int, k0);
    pk.y = __builtin_bit_cast(unsigned int, k1);
    pv.x = __builtin_bit_cast(unsigned int, v0);
    pv.y = __builtin_bit_cast(unsigned int, v1);
    *(uint2*)(kh + tid * 2) = pk;
    *(uint2*)(vh + tid * 2) = pv;
}

__device__ __forceinline__ float f16lo(unsigned int u) {
    return __low2float(__builtin_bit_cast(__half2, u));
}
__device__ __forceinline__ float f16hi(unsigned int u) {
    return __high2float(__builtin_bit_cast(__half2, u));
}

__device__ __forceinline__ float dot2f(unsigned int ku, h2_t qh, float c) {
#if __has_builtin(__builtin_amdgcn_fdot2)
    return __builtin_amdgcn_fdot2(__builtin_bit_cast(h2_t, ku), qh, c, false);
#else
    return c + f16lo(ku) * (float)qh.x + f16hi(ku) * (float)qh.y;
#endif
}

// ---------------- main kernel (f16 gathers, compacted) ----------------
__global__ __launch_bounds__(WPB * 64)
void wayfinder_attn_f16(const float* __restrict__ q,
                        const unsigned int* __restrict__ kvws,
                        const float* __restrict__ etb,
                        const int*   __restrict__ neigh_idx,
                        const int*   __restrict__ edge_type,
                        float*       __restrict__ out)
{
    __shared__ int   j_s[WPB][NB];
    __shared__ float b_s[WPB][NB];
    __shared__ float w_s[WPB][NB];
    __shared__ float dot_s[WPB][NB];

    const int lane = threadIdx.x & 63;
    const int wave = threadIdx.x >> 6;
    const int wq   = blockIdx.x * WPB + wave;       // flat h*T + t (B=1)
    const int t    = wq & (T_DIM - 1);
    const int qbase    = wq * DH;
    const int headbase = (wq - t) * DH;             // floats
    const unsigned int* __restrict__ kh = kvws + (headbase >> 1);
    const unsigned int* __restrict__ vh = kvws + (KV_ELEMS / 2) + (headbase >> 1);

    // init padding (entries >= nv read as row 0 / bias 0)
    j_s[wave][lane] = 0;
    b_s[wave][lane] = 0.f;

    // per-lane neighbor metadata (lane d owns raw neighbor slot d)
    const int raw = neigh_idx[wq * NB + lane];
    const int et  = edge_type[wq * NB + lane];
    const bool valid = (raw >= 0) && (raw <= t);
    const int  sj    = min(max(raw, 0), T_DIM - 1);
    const float bias = (et != 0) ? etb[et - 1] : 0.f;

    // compaction: valid entries -> positions [0, nv)
    const unsigned long long vb = __ballot(valid);
    const int nv  = __popcll(vb);
    const int pos = __popcll(vb & ((1ull << lane) - 1ull));
    if (valid) { j_s[wave][pos] = sj; b_s[wave][pos] = bias; }

    // ---- score phase (interleaved): iteration i covers entries i*8..i*8+7;
    //      group g8 handles entry e = i*8+g8. Guard i*8<nv is wave-uniform. ----
    const int c8 = lane & 7;
    const int g8 = lane >> 3;
    const float4 qv0 = *(const float4*)(q + qbase + c8 * 8);
    const float4 qv1 = *(const float4*)(q + qbase + c8 * 8 + 4);
    // q pre-rounded to packed f16 for v_dot2_f32_f16
    const h2_t qh0 = { (_Float16)qv0.x, (_Float16)qv0.y };
    const h2_t qh1 = { (_Float16)qv0.z, (_Float16)qv0.w };
    const h2_t qh2 = { (_Float16)qv1.x, (_Float16)qv1.y };
    const h2_t qh3 = { (_Float16)qv1.z, (_Float16)qv1.w };

    // K prefetch: up to ceil(nv/8) independent dwordx4 loads in flight.
    uint4 kr[8];
    #pragma unroll
    for (int i = 0; i < 8; ++i) {
        if (i * 8 < nv) {
            const int je = j_s[wave][i * 8 + g8];   // entries >= nv -> row 0 (safe)
            kr[i] = *(const uint4*)(kh + je * 32 + c8 * 4);  // dims 8c8..8c8+7
        }
    }

    // V prefetch (R11 delta): addresses depend only on indices, not weights,
    // so issue all PV gathers now — latency overlaps score+softmax below.
    const int qw   = lane >> 4;      // quarter 0..3
    const int lp16 = lane & 15;      // dims 4*lp16..4*lp16+3
    uint2 vr[4][4];
    #pragma unroll
    for (int b = 0; b < 4; ++b) {
        if (b * 16 < nv) {
            const int eb = b * 16 + qw * 4;
            const int4 jd = *(const int4*)&j_s[wave][eb];
            vr[b][0] = *(const uint2*)(vh + jd.x * 32 + lp16 * 2);
            vr[b][1] = *(const uint2*)(vh + jd.y * 32 + lp16 * 2);
            vr[b][2] = *(const uint2*)(vh + jd.z * 32 + lp16 * 2);
            vr[b][3] = *(const uint2*)(vh + jd.w * 32 + lp16 * 2);
        }
    }

    // score compute (consumes kr while vr is in flight)
    #pragma unroll
    for (int i = 0; i < 8; ++i) {
        if (i * 8 < nv) {
            const uint4 u = kr[i];
            float p = dot2f(u.x, qh0, 0.f);
            p = dot2f(u.y, qh1, p);
            p = dot2f(u.z, qh2, p);
            p = dot2f(u.w, qh3, p);
            p += __shfl_xor(p, 1, 64);
            p += __shfl_xor(p, 2, 64);
            p += __shfl_xor(p, 4, 64);
            if (c8 == 0) dot_s[wave][i * 8 + g8] = p;   // capture entry e
        }
    }
    const float mydot = dot_s[wave][lane];   // entry 'lane' (garbage if >= nv)

    // ---- softmax over compacted entries (lane d = entry d) ----
    const bool dval = lane < nv;
    const float score = dval ? (mydot * 0.125f + b_s[wave][lane]) : -INFINITY;
    float m = score;
    #pragma unroll
    for (int o = 32; o > 0; o >>= 1) m = fmaxf(m, __shfl_xor(m, o, 64));
    const float e = dval ? __expf(score - m) : 0.f;
    float s = e;
    #pragma unroll
    for (int o = 32; o > 0; o >>= 1) s += __shfl_xor(s, o, 64);
    const float w = e / fmaxf(s, 1e-20f);
    w_s[wave][lane] = w;   // entries >= nv get w=0 (padding-safe)

    // ---- PV FMA: consume prefetched vr with weight broadcasts; f32 accum.
    //      Same order/ops as R10 -> bit-identical numerics. ----
    float a0 = 0.f, a1 = 0.f, a2 = 0.f, a3 = 0.f;
    #pragma unroll
    for (int b = 0; b < 4; ++b) {
        if (b * 16 < nv) {
            const int eb = b * 16 + qw * 4;
            const float4 wd = *(const float4*)&w_s[wave][eb];
            a0 += wd.x * f16lo(vr[b][0].x);  a1 += wd.x * f16hi(vr[b][0].x);
            a2 += wd.x * f16lo(vr[b][0].y);  a3 += wd.x * f16hi(vr[b][0].y);
            a0 += wd.y * f16lo(vr[b][1].x);  a1 += wd.y * f16hi(vr[b][1].x);
            a2 += wd.y * f16lo(vr[b][1].y);  a3 += wd.y * f16hi(vr[b][1].y);
            a0 += wd.z * f16lo(vr[b][2].x);  a1 += wd.z * f16hi(vr[b][2].x);
            a2 += wd.z * f16lo(vr[b][2].y);  a3 += wd.z * f16hi(vr[b][2].y);
            a0 += wd.w * f16lo(vr[b][3].x);  a1 += wd.w * f16hi(vr[b][3].x);
            a2 += wd.w * f16lo(vr[b][3].y);  a3 += wd.w * f16hi(vr[b][3].y);
        }
    }
    // reduce across quarters (butterfly), then lanes 0..15 store float4
    a0 += __shfl_xor(a0, 16, 64);  a1 += __shfl_xor(a1, 16, 64);
    a2 += __shfl_xor(a2, 16, 64);  a3 += __shfl_xor(a3, 16, 64);
    a0 += __shfl_xor(a0, 32, 64);  a1 += __shfl_xor(a1, 32, 64);
    a2 += __shfl_xor(a2, 32, 64);  a3 += __shfl_xor(a3, 32, 64);
    if (lane < 16) {
        float4 o; o.x = a0; o.y = a1; o.z = a2; o.w = a3;
        *(float4*)(out + qbase + lane * 4) = o;
    }
}

// ---------------- fallback (R3, f32, no workspace) ----------------
__global__ __launch_bounds__(WPB * 64)
void wayfinder_attn_f32(const float* __restrict__ q,
                        const float* __restrict__ k,
                        const float* __restrict__ v,
                        const float* __restrict__ etb,
                        const int*   __restrict__ neigh_idx,
                        const int*   __restrict__ edge_type,
                        float*       __restrict__ out)
{
    __shared__ int   j_s[WPB][NB];
    __shared__ float w_s[WPB][NB];

    const int lane = threadIdx.x & 63;
    const int wave = threadIdx.x >> 6;
    const int wq   = blockIdx.x * WPB + wave;
    const int t    = wq & (T_DIM - 1);
    const long long qbase    = (long long)wq * DH;
    const long long headbase = (long long)(wq - t) * DH;

    const long long nbase = (long long)wq * NB;
    const int raw = neigh_idx[nbase + lane];
    const int et  = edge_type[nbase + lane];
    const bool valid = (raw >= 0) && (raw <= t);
    const int  sj   = min(max(raw, 0), T_DIM - 1);
    j_s[wave][lane] = sj;

    const int c = lane & 15;
    const int g = lane >> 4;
    const float4 qv = *(const float4*)(q + qbase + c * 4);

    int jarr[16];
    {
        const int4* jg = (const int4*)&j_s[wave][g * 16];
        *(int4*)&jarr[0]  = jg[0];
        *(int4*)&jarr[4]  = jg[1];
        *(int4*)&jarr[8]  = jg[2];
        *(int4*)&jarr[12] = jg[3];
    }

    const float* __restrict__ khead = k + headbase;
    float mydot = 0.f;
    #pragma unroll
    for (int i = 0; i < 16; ++i) {
        const float4 kv = *(const float4*)(khead + (long long)jarr[i] * DH + c * 4);
        float p = kv.x * qv.x + kv.y * qv.y + kv.z * qv.z + kv.w * qv.w;
        p += __shfl_xor(p, 1, 64);
        p += __shfl_xor(p, 2, 64);
        p += __shfl_xor(p, 4, 64);
        p += __shfl_xor(p, 8, 64);
        if (c == i) mydot = p;
    }

    const float bias  = (et != 0) ? etb[et - 1] : 0.f;
    const float score = valid ? (mydot * 0.125f + bias) : -INFINITY;

    float m = score;
    #pragma unroll
    for (int o = 32; o > 0; o >>= 1) m = fmaxf(m, __shfl_xor(m, o, 64));
    const float e = valid ? __expf(score - m) : 0.f;
    float s = e;
    #pragma unroll
    for (int o = 32; o > 0; o >>= 1) s += __shfl_xor(s, o, 64);
    const float w = e / fmaxf(s, 1e-20f);
    w_s[wave][lane] = w;

    const float* __restrict__ vhead = v + headbase;
    float acc = 0.f;
    #pragma unroll
    for (int d4 = 0; d4 < 16; ++d4) {
        const float4 wd = *(const float4*)&w_s[wave][d4 * 4];
        const int4   jd = *(const int4*)&j_s[wave][d4 * 4];
        acc += wd.x * vhead[(long long)jd.x * DH + lane];
        acc += wd.y * vhead[(long long)jd.y * DH + lane];
        acc += wd.z * vhead[(long long)jd.z * DH + lane];
        acc += wd.w * vhead[(long long)jd.w * DH + lane];
    }
    out[qbase + lane] = acc;
}

extern "C" void kernel_launch(void* const* d_in, const int* in_sizes, int n_in,
                              void* d_out, int out_size, void* d_ws, size_t ws_size,
                              hipStream_t stream)
{
    const float* q   = (const float*)d_in[0];
    const float* k   = (const float*)d_in[1];
    const float* v   = (const float*)d_in[2];
    const float* etb = (const float*)d_in[3];
    const int* neigh_idx = (const int*)d_in[4];
    const int* edge_type = (const int*)d_in[5];
    float* out = (float*)d_out;

    const int total_queries = 16 * T_DIM;     // 32768
    const int blocks = total_queries / WPB;   // 8192
    const size_t need = (size_t)KV_ELEMS * 2 * sizeof(unsigned short); // 8 MB

    if (ws_size >= need) {
        unsigned int* ws = (unsigned int*)d_ws;
        hipLaunchKernelGGL(convert_kv_kernel, dim3(KV_ELEMS / 4 / 256), dim3(256),
                           0, stream, k, v, ws);
        hipLaunchKernelGGL(wayfinder_attn_f16, dim3(blocks), dim3(WPB * 64),
                           0, stream, q, ws, etb, neigh_idx, edge_type, out);
    } else {
        hipLaunchKernelGGL(wayfinder_attn_f32, dim3(blocks), dim3(WPB * 64),
                           0, stream, q, k, v, etb, neigh_idx, edge_type, out);
    }
}

// Round 12
// 114.918 us; speedup vs baseline: 1.0388x; 1.0388x over previous
//
#include <hip/hip_runtime.h>
#include <hip/hip_fp16.h>
#include <math.h>

// WayfinderAttention: B=1, H=16, T=2048, DH=64, D=64 neighbors. f32 in/out.
// R12: R10 exact (passed, 111.9us, absmax 0.015625) + MINIMAL V-prefetch:
//      only PV block 0 (8 VGPRs) hoisted above softmax so its latency
//      overlaps the softmax shuffles; blocks 1-3 load in-loop as in R10.
//      (R11's full 32-VGPR prefetch regressed via occupancy loss.)
// Fallback to the proven R3 f32 kernel if ws_size < 8 MB.

#define T_DIM 2048
#define DH    64
#define NB    64
#define WPB   4
#define KV_ELEMS (16 * T_DIM * DH)   // 2,097,152 per tensor

typedef _Float16 h2_t __attribute__((ext_vector_type(2)));

// ---------------- prepass: f32 -> f16 (RTN), K then V ----------------
__global__ __launch_bounds__(256)
void convert_kv_kernel(const float* __restrict__ k, const float* __restrict__ v,
                       unsigned int* __restrict__ ws)
{
    const int tid = blockIdx.x * 256 + threadIdx.x;     // [0, KV_ELEMS/4)
    unsigned int* kh = ws;
    unsigned int* vh = ws + (KV_ELEMS / 2);
    const float4 kv = *(const float4*)(k + (long long)tid * 4);
    const float4 vv = *(const float4*)(v + (long long)tid * 4);
    h2_t k0 = { (_Float16)kv.x, (_Float16)kv.y };
    h2_t k1 = { (_Float16)kv.z, (_Float16)kv.w };
    h2_t v0 = { (_Float16)vv.x, (_Float16)vv.y };
    h2_t v1 = { (_Float16)vv.z, (_Float16)vv.w };
    uint2 pk, pv;
    pk.x = __builtin_bit_cast(unsigned int, k0);
    pk.y = __builtin_bit_cast(unsigned int, k1);
    pv.x = __builtin_bit_cast(unsigned int, v0);
    pv.y = __builtin_bit_cast(unsigned int, v1);
    *(uint2*)(kh + tid * 2) = pk;
    *(uint2*)(vh + tid * 2) = pv;
}

__device__ __forceinline__ float f16lo(unsigned int u) {
    return __low2float(__builtin_bit_cast(__half2, u));
}
__device__ __forceinline__ float f16hi(unsigned int u) {
    return __high2float(__builtin_bit_cast(__half2, u));
}

__device__ __forceinline__ float dot2f(unsigned int ku, h2_t qh, float c) {
#if __has_builtin(__builtin_amdgcn_fdot2)
    return __builtin_amdgcn_fdot2(__builtin_bit_cast(h2_t, ku), qh, c, false);
#else
    return c + f16lo(ku) * (float)qh.x + f16hi(ku) * (float)qh.y;
#endif
}

// ---------------- main kernel (f16 gathers, compacted) ----------------
__global__ __launch_bounds__(WPB * 64)
void wayfinder_attn_f16(const float* __restrict__ q,
                        const unsigned int* __restrict__ kvws,
                        const float* __restrict__ etb,
                        const int*   __restrict__ neigh_idx,
                        const int*   __restrict__ edge_type,
                        float*       __restrict__ out)
{
    __shared__ int   j_s[WPB][NB];
    __shared__ float b_s[WPB][NB];
    __shared__ float w_s[WPB][NB];
    __shared__ float dot_s[WPB][NB];

    const int lane = threadIdx.x & 63;
    const int wave = threadIdx.x >> 6;
    const int wq   = blockIdx.x * WPB + wave;       // flat h*T + t (B=1)
    const int t    = wq & (T_DIM - 1);
    const int qbase    = wq * DH;
    const int headbase = (wq - t) * DH;             // floats
    const unsigned int* __restrict__ kh = kvws + (headbase >> 1);
    const unsigned int* __restrict__ vh = kvws + (KV_ELEMS / 2) + (headbase >> 1);

    // init padding (entries >= nv read as row 0 / bias 0)
    j_s[wave][lane] = 0;
    b_s[wave][lane] = 0.f;

    // per-lane neighbor metadata (lane d owns raw neighbor slot d)
    const int raw = neigh_idx[wq * NB + lane];
    const int et  = edge_type[wq * NB + lane];
    const bool valid = (raw >= 0) && (raw <= t);
    const int  sj    = min(max(raw, 0), T_DIM - 1);
    const float bias = (et != 0) ? etb[et - 1] : 0.f;

    // compaction: valid entries -> positions [0, nv)
    const unsigned long long vb = __ballot(valid);
    const int nv  = __popcll(vb);
    const int pos = __popcll(vb & ((1ull << lane) - 1ull));
    if (valid) { j_s[wave][pos] = sj; b_s[wave][pos] = bias; }

    // ---- score phase (interleaved): iteration i covers entries i*8..i*8+7;
    //      group g8 handles entry e = i*8+g8. Guard i*8<nv is wave-uniform. ----
    const int c8 = lane & 7;
    const int g8 = lane >> 3;
    const float4 qv0 = *(const float4*)(q + qbase + c8 * 8);
    const float4 qv1 = *(const float4*)(q + qbase + c8 * 8 + 4);
    // q pre-rounded to packed f16 for v_dot2_f32_f16
    const h2_t qh0 = { (_Float16)qv0.x, (_Float16)qv0.y };
    const h2_t qh1 = { (_Float16)qv0.z, (_Float16)qv0.w };
    const h2_t qh2 = { (_Float16)qv1.x, (_Float16)qv1.y };
    const h2_t qh3 = { (_Float16)qv1.z, (_Float16)qv1.w };

    // K prefetch: up to ceil(nv/8) independent dwordx4 loads in flight.
    uint4 kr[8];
    #pragma unroll
    for (int i = 0; i < 8; ++i) {
        if (i * 8 < nv) {
            const int je = j_s[wave][i * 8 + g8];   // entries >= nv -> row 0 (safe)
            kr[i] = *(const uint4*)(kh + je * 32 + c8 * 4);  // dims 8c8..8c8+7
        }
    }

    // R12 delta: prefetch ONLY PV block 0 (8 VGPRs) so its V latency overlaps
    // the softmax below. Blocks 1-3 load in-loop exactly as R10.
    const int qw   = lane >> 4;      // quarter 0..3
    const int lp16 = lane & 15;      // dims 4*lp16..4*lp16+3
    uint2 v0r0, v0r1, v0r2, v0r3;
    if (nv > 0) {
        const int4 jd0 = *(const int4*)&j_s[wave][qw * 4];
        v0r0 = *(const uint2*)(vh + jd0.x * 32 + lp16 * 2);
        v0r1 = *(const uint2*)(vh + jd0.y * 32 + lp16 * 2);
        v0r2 = *(const uint2*)(vh + jd0.z * 32 + lp16 * 2);
        v0r3 = *(const uint2*)(vh + jd0.w * 32 + lp16 * 2);
    }

    // score compute (consumes kr while block-0 V is in flight)
    #pragma unroll
    for (int i = 0; i < 8; ++i) {
        if (i * 8 < nv) {
            const uint4 u = kr[i];
            float p = dot2f(u.x, qh0, 0.f);
            p = dot2f(u.y, qh1, p);
            p = dot2f(u.z, qh2, p);
            p = dot2f(u.w, qh3, p);
            p += __shfl_xor(p, 1, 64);
            p += __shfl_xor(p, 2, 64);
            p += __shfl_xor(p, 4, 64);
            if (c8 == 0) dot_s[wave][i * 8 + g8] = p;   // capture entry e
        }
    }
    const float mydot = dot_s[wave][lane];   // entry 'lane' (garbage if >= nv)

    // ---- softmax over compacted entries (lane d = entry d) ----
    const bool dval = lane < nv;
    const float score = dval ? (mydot * 0.125f + b_s[wave][lane]) : -INFINITY;
    float m = score;
    #pragma unroll
    for (int o = 32; o > 0; o >>= 1) m = fmaxf(m, __shfl_xor(m, o, 64));
    const float e = dval ? __expf(score - m) : 0.f;
    float s = e;
    #pragma unroll
    for (int o = 32; o > 0; o >>= 1) s += __shfl_xor(s, o, 64);
    const float w = e / fmaxf(s, 1e-20f);
    w_s[wave][lane] = w;   // entries >= nv get w=0 (padding-safe)

    // ---- PV: block 0 from prefetched registers; blocks 1-3 as in R10.
    //      Same FMA order as R10 -> numerics bit-identical. ----
    float a0 = 0.f, a1 = 0.f, a2 = 0.f, a3 = 0.f;
    if (nv > 0) {
        const float4 wd = *(const float4*)&w_s[wave][qw * 4];
        a0 += wd.x * f16lo(v0r0.x);  a1 += wd.x * f16hi(v0r0.x);
        a2 += wd.x * f16lo(v0r0.y);  a3 += wd.x * f16hi(v0r0.y);
        a0 += wd.y * f16lo(v0r1.x);  a1 += wd.y * f16hi(v0r1.x);
        a2 += wd.y * f16lo(v0r1.y);  a3 += wd.y * f16hi(v0r1.y);
        a0 += wd.z * f16lo(v0r2.x);  a1 += wd.z * f16hi(v0r2.x);
        a2 += wd.z * f16lo(v0r2.y);  a3 += wd.z * f16hi(v0r2.y);
        a0 += wd.w * f16lo(v0r3.x);  a1 += wd.w * f16hi(v0r3.x);
        a2 += wd.w * f16lo(v0r3.y);  a3 += wd.w * f16hi(v0r3.y);
    }
    for (int base = 16; base < nv; base += 16) {
        const int eb = base + qw * 4;
        const int4   jd = *(const int4*)&j_s[wave][eb];
        const float4 wd = *(const float4*)&w_s[wave][eb];
        const uint2 u0 = *(const uint2*)(vh + jd.x * 32 + lp16 * 2);
        const uint2 u1 = *(const uint2*)(vh + jd.y * 32 + lp16 * 2);
        const uint2 u2 = *(const uint2*)(vh + jd.z * 32 + lp16 * 2);
        const uint2 u3 = *(const uint2*)(vh + jd.w * 32 + lp16 * 2);
        a0 += wd.x * f16lo(u0.x);  a1 += wd.x * f16hi(u0.x);
        a2 += wd.x * f16lo(u0.y);  a3 += wd.x * f16hi(u0.y);
        a0 += wd.y * f16lo(u1.x);  a1 += wd.y * f16hi(u1.x);
        a2 += wd.y * f16lo(u1.y);  a3 += wd.y * f16hi(u1.y);
        a0 += wd.z * f16lo(u2.x);  a1 += wd.z * f16hi(u2.x);
        a2 += wd.z * f16lo(u2.y);  a3 += wd.z * f16hi(u2.y);
        a0 += wd.w * f16lo(u3.x);  a1 += wd.w * f16hi(u3.x);
        a2 += wd.w * f16lo(u3.y);  a3 += wd.w * f16hi(u3.y);
    }
    // reduce across quarters (butterfly), then lanes 0..15 store float4
    a0 += __shfl_xor(a0, 16, 64);  a1 += __shfl_xor(a1, 16, 64);
    a2 += __shfl_xor(a2, 16, 64);  a3 += __shfl_xor(a3, 16, 64);
    a0 += __shfl_xor(a0, 32, 64);  a1 += __shfl_xor(a1, 32, 64);
    a2 += __shfl_xor(a2, 32, 64);  a3 += __shfl_xor(a3, 32, 64);
    if (lane < 16) {
        float4 o; o.x = a0; o.y = a1; o.z = a2; o.w = a3;
        *(float4*)(out + qbase + lane * 4) = o;
    }
}

// ---------------- fallback (R3, f32, no workspace) ----------------
__global__ __launch_bounds__(WPB * 64)
void wayfinder_attn_f32(const float* __restrict__ q,
                        const float* __restrict__ k,
                        const float* __restrict__ v,
                        const float* __restrict__ etb,
                        const int*   __restrict__ neigh_idx,
                        const int*   __restrict__ edge_type,
                        float*       __restrict__ out)
{
    __shared__ int   j_s[WPB][NB];
    __shared__ float w_s[WPB][NB];

    const int lane = threadIdx.x & 63;
    const int wave = threadIdx.x >> 6;
    const int wq   = blockIdx.x * WPB + wave;
    const int t    = wq & (T_DIM - 1);
    const long long qbase    = (long long)wq * DH;
    const long long headbase = (long long)(wq - t) * DH;

    const long long nbase = (long long)wq * NB;
    const int raw = neigh_idx[nbase + lane];
    const int et  = edge_type[nbase + lane];
    const bool valid = (raw >= 0) && (raw <= t);
    const int  sj   = min(max(raw, 0), T_DIM - 1);
    j_s[wave][lane] = sj;

    const int c = lane & 15;
    const int g = lane >> 4;
    const float4 qv = *(const float4*)(q + qbase + c * 4);

    int jarr[16];
    {
        const int4* jg = (const int4*)&j_s[wave][g * 16];
        *(int4*)&jarr[0]  = jg[0];
        *(int4*)&jarr[4]  = jg[1];
        *(int4*)&jarr[8]  = jg[2];
        *(int4*)&jarr[12] = jg[3];
    }

    const float* __restrict__ khead = k + headbase;
    float mydot = 0.f;
    #pragma unroll
    for (int i = 0; i < 16; ++i) {
        const float4 kv = *(const float4*)(khead + (long long)jarr[i] * DH + c * 4);
        float p = kv.x * qv.x + kv.y * qv.y + kv.z * qv.z + kv.w * qv.w;
        p += __shfl_xor(p, 1, 64);
        p += __shfl_xor(p, 2, 64);
        p += __shfl_xor(p, 4, 64);
        p += __shfl_xor(p, 8, 64);
        if (c == i) mydot = p;
    }

    const float bias  = (et != 0) ? etb[et - 1] : 0.f;
    const float score = valid ? (mydot * 0.125f + bias) : -INFINITY;

    float m = score;
    #pragma unroll
    for (int o = 32; o > 0; o >>= 1) m = fmaxf(m, __shfl_xor(m, o, 64));
    const float e = valid ? __expf(score - m) : 0.f;
    float s = e;
    #pragma unroll
    for (int o = 32; o > 0; o >>= 1) s += __shfl_xor(s, o, 64);
    const float w = e / fmaxf(s, 1e-20f);
    w_s[wave][lane] = w;

    const float* __restrict__ vhead = v + headbase;
    float acc = 0.f;
    #pragma unroll
    for (int d4 = 0; d4 < 16; ++d4) {
        const float4 wd = *(const float4*)&w_s[wave][d4 * 4];
        const int4   jd = *(const int4*)&j_s[wave][d4 * 4];
        acc += wd.x * vhead[(long long)jd.x * DH + lane];
        acc += wd.y * vhead[(long long)jd.y * DH + lane];
        acc += wd.z * vhead[(long long)jd.z * DH + lane];
        acc += wd.w * vhead[(long long)jd.w * DH + lane];
    }
    out[qbase + lane] = acc;
}

extern "C" void kernel_launch(void* const* d_in, const int* in_sizes, int n_in,
                              void* d_out, int out_size, void* d_ws, size_t ws_size,
                              hipStream_t stream)
{
    const float* q   = (const float*)d_in[0];
    const float* k   = (const float*)d_in[1];
    const float* v   = (const float*)d_in[2];
    const float* etb = (const float*)d_in[3];
    const int* neigh_idx = (const int*)d_in[4];
    const int* edge_type = (const int*)d_in[5];
    float* out = (float*)d_out;

    const int total_queries = 16 * T_DIM;     // 32768
    const int blocks = total_queries / WPB;   // 8192
    const size_t need = (size_t)KV_ELEMS * 2 * sizeof(unsigned short); // 8 MB

    if (ws_size >= need) {
        unsigned int* ws = (unsigned int*)d_ws;
        hipLaunchKernelGGL(convert_kv_kernel, dim3(KV_ELEMS / 4 / 256), dim3(256),
                           0, stream, k, v, ws);
        hipLaunchKernelGGL(wayfinder_attn_f16, dim3(blocks), dim3(WPB * 64),
                           0, stream, q, ws, etb, neigh_idx, edge_type, out);
    } else {
        hipLaunchKernelGGL(wayfinder_attn_f32, dim3(blocks), dim3(WPB * 64),
                           0, stream, q, k, v, etb, neigh_idx, edge_type, out);
    }
}

// Round 13
// 114.295 us; speedup vs baseline: 1.0445x; 1.0054x over previous
//
#include <hip/hip_runtime.h>
#include <hip/hip_fp16.h>
#include <math.h>

// WayfinderAttention: B=1, H=16, T=2048, DH=64, D=64 neighbors. f32 in/out.
// FINAL (= R10, best: 111.9us total, absmax 0.015625):
//  - prepass converts K,V to f16 (RTN) in d_ws (halves gather bytes/requests)
//  - one wave per query; valid neighbors compacted via ballot+prefix-popcount
//  - score: interleaved mapping (iter i covers entries i*8..i*8+7, group g8
//    handles e=i*8+g8) -> wave-uniform trip count ceil(nv/8); K chunks
//    register-prefetched (8 dwordx4 in flight); inner product via
//    v_dot2_f32_f16; owner capture through LDS dot_s
//  - softmax f32, weights f32 in LDS (half-precision PV accum was the R5/R6
//    bug -- never reintroduce)
//  - PV: quarter-wave per row, 16 lanes x 8B, weight/index via vector LDS
//    broadcasts, f32 accumulate; cross-quarter butterfly; float4 store
//  - R11/R12 deep V-prefetch variants regressed (VGPR pressure beats
//    per-wave latency hiding at ~12 waves/CU) -- excluded deliberately.
// Fallback to the proven R3 f32 kernel if ws_size < 8 MB.

#define T_DIM 2048
#define DH    64
#define NB    64
#define WPB   4
#define KV_ELEMS (16 * T_DIM * DH)   // 2,097,152 per tensor

typedef _Float16 h2_t __attribute__((ext_vector_type(2)));

// ---------------- prepass: f32 -> f16 (RTN), K then V ----------------
__global__ __launch_bounds__(256)
void convert_kv_kernel(const float* __restrict__ k, const float* __restrict__ v,
                       unsigned int* __restrict__ ws)
{
    const int tid = blockIdx.x * 256 + threadIdx.x;     // [0, KV_ELEMS/4)
    unsigned int* kh = ws;
    unsigned int* vh = ws + (KV_ELEMS / 2);
    const float4 kv = *(const float4*)(k + (long long)tid * 4);
    const float4 vv = *(const float4*)(v + (long long)tid * 4);
    h2_t k0 = { (_Float16)kv.x, (_Float16)kv.y };
    h2_t k1 = { (_Float16)kv.z, (_Float16)kv.w };
    h2_t v0 = { (_Float16)vv.x, (_Float16)vv.y };
    h2_t v1 = { (_Float16)vv.z, (_Float16)vv.w };
    uint2 pk, pv;
    pk.x = __builtin_bit_cast(unsigned int, k0);
    pk.y = __builtin_bit_cast(unsigned int, k1);
    pv.x = __builtin_bit_cast(unsigned int, v0);
    pv.y = __builtin_bit_cast(unsigned int, v1);
    *(uint2*)(kh + tid * 2) = pk;
    *(uint2*)(vh + tid * 2) = pv;
}

__device__ __forceinline__ float f16lo(unsigned int u) {
    return __low2float(__builtin_bit_cast(__half2, u));
}
__device__ __forceinline__ float f16hi(unsigned int u) {
    return __high2float(__builtin_bit_cast(__half2, u));
}

__device__ __forceinline__ float dot2f(unsigned int ku, h2_t qh, float c) {
#if __has_builtin(__builtin_amdgcn_fdot2)
    return __builtin_amdgcn_fdot2(__builtin_bit_cast(h2_t, ku), qh, c, false);
#else
    return c + f16lo(ku) * (float)qh.x + f16hi(ku) * (float)qh.y;
#endif
}

// ---------------- main kernel (f16 gathers, compacted) ----------------
__global__ __launch_bounds__(WPB * 64)
void wayfinder_attn_f16(const float* __restrict__ q,
                        const unsigned int* __restrict__ kvws,
                        const float* __restrict__ etb,
                        const int*   __restrict__ neigh_idx,
                        const int*   __restrict__ edge_type,
                        float*       __restrict__ out)
{
    __shared__ int   j_s[WPB][NB];
    __shared__ float b_s[WPB][NB];
    __shared__ float w_s[WPB][NB];
    __shared__ float dot_s[WPB][NB];

    const int lane = threadIdx.x & 63;
    const int wave = threadIdx.x >> 6;
    const int wq   = blockIdx.x * WPB + wave;       // flat h*T + t (B=1)
    const int t    = wq & (T_DIM - 1);
    const int qbase    = wq * DH;
    const int headbase = (wq - t) * DH;             // floats
    const unsigned int* __restrict__ kh = kvws + (headbase >> 1);
    const unsigned int* __restrict__ vh = kvws + (KV_ELEMS / 2) + (headbase >> 1);

    // init padding (entries >= nv read as row 0 / bias 0)
    j_s[wave][lane] = 0;
    b_s[wave][lane] = 0.f;

    // per-lane neighbor metadata (lane d owns raw neighbor slot d)
    const int raw = neigh_idx[wq * NB + lane];
    const int et  = edge_type[wq * NB + lane];
    const bool valid = (raw >= 0) && (raw <= t);
    const int  sj    = min(max(raw, 0), T_DIM - 1);
    const float bias = (et != 0) ? etb[et - 1] : 0.f;

    // compaction: valid entries -> positions [0, nv)
    const unsigned long long vb = __ballot(valid);
    const int nv  = __popcll(vb);
    const int pos = __popcll(vb & ((1ull << lane) - 1ull));
    if (valid) { j_s[wave][pos] = sj; b_s[wave][pos] = bias; }

    // ---- score phase (interleaved): iteration i covers entries i*8..i*8+7;
    //      group g8 handles entry e = i*8+g8. Guard i*8<nv is wave-uniform. ----
    const int c8 = lane & 7;
    const int g8 = lane >> 3;
    const float4 qv0 = *(const float4*)(q + qbase + c8 * 8);
    const float4 qv1 = *(const float4*)(q + qbase + c8 * 8 + 4);
    // q pre-rounded to packed f16 for v_dot2_f32_f16
    const h2_t qh0 = { (_Float16)qv0.x, (_Float16)qv0.y };
    const h2_t qh1 = { (_Float16)qv0.z, (_Float16)qv0.w };
    const h2_t qh2 = { (_Float16)qv1.x, (_Float16)qv1.y };
    const h2_t qh3 = { (_Float16)qv1.z, (_Float16)qv1.w };

    // K prefetch: up to ceil(nv/8) independent dwordx4 loads in flight.
    uint4 kr[8];
    #pragma unroll
    for (int i = 0; i < 8; ++i) {
        if (i * 8 < nv) {
            const int je = j_s[wave][i * 8 + g8];   // entries >= nv -> row 0 (safe)
            kr[i] = *(const uint4*)(kh + je * 32 + c8 * 4);  // dims 8c8..8c8+7
        }
    }

    #pragma unroll
    for (int i = 0; i < 8; ++i) {
        if (i * 8 < nv) {
            const uint4 u = kr[i];
            float p = dot2f(u.x, qh0, 0.f);
            p = dot2f(u.y, qh1, p);
            p = dot2f(u.z, qh2, p);
            p = dot2f(u.w, qh3, p);
            p += __shfl_xor(p, 1, 64);
            p += __shfl_xor(p, 2, 64);
            p += __shfl_xor(p, 4, 64);
            if (c8 == 0) dot_s[wave][i * 8 + g8] = p;   // capture entry e
        }
    }
    const float mydot = dot_s[wave][lane];   // entry 'lane' (garbage if >= nv)

    // ---- softmax over compacted entries (lane d = entry d) ----
    const bool dval = lane < nv;
    const float score = dval ? (mydot * 0.125f + b_s[wave][lane]) : -INFINITY;
    float m = score;
    #pragma unroll
    for (int o = 32; o > 0; o >>= 1) m = fmaxf(m, __shfl_xor(m, o, 64));
    const float e = dval ? __expf(score - m) : 0.f;
    float s = e;
    #pragma unroll
    for (int o = 32; o > 0; o >>= 1) s += __shfl_xor(s, o, 64);
    const float w = e / fmaxf(s, 1e-20f);
    w_s[wave][lane] = w;   // entries >= nv get w=0 (padding-safe)

    // ---- PV: quarter qw takes contiguous entries base+qw*4..+3 (vector LDS
    //      broadcasts); 16 lanes x 8B per V row; f32 accumulate ----
    const int qw   = lane >> 4;      // quarter 0..3
    const int lp16 = lane & 15;      // dims 4*lp16..4*lp16+3
    float a0 = 0.f, a1 = 0.f, a2 = 0.f, a3 = 0.f;
    for (int base = 0; base < nv; base += 16) {
        const int eb = base + qw * 4;
        const int4   jd = *(const int4*)&j_s[wave][eb];
        const float4 wd = *(const float4*)&w_s[wave][eb];
        const uint2 u0 = *(const uint2*)(vh + jd.x * 32 + lp16 * 2);
        const uint2 u1 = *(const uint2*)(vh + jd.y * 32 + lp16 * 2);
        const uint2 u2 = *(const uint2*)(vh + jd.z * 32 + lp16 * 2);
        const uint2 u3 = *(const uint2*)(vh + jd.w * 32 + lp16 * 2);
        a0 += wd.x * f16lo(u0.x);  a1 += wd.x * f16hi(u0.x);
        a2 += wd.x * f16lo(u0.y);  a3 += wd.x * f16hi(u0.y);
        a0 += wd.y * f16lo(u1.x);  a1 += wd.y * f16hi(u1.x);
        a2 += wd.y * f16lo(u1.y);  a3 += wd.y * f16hi(u1.y);
        a0 += wd.z * f16lo(u2.x);  a1 += wd.z * f16hi(u2.x);
        a2 += wd.z * f16lo(u2.y);  a3 += wd.z * f16hi(u2.y);
        a0 += wd.w * f16lo(u3.x);  a1 += wd.w * f16hi(u3.x);
        a2 += wd.w * f16lo(u3.y);  a3 += wd.w * f16hi(u3.y);
    }
    // reduce across quarters (butterfly), then lanes 0..15 store float4
    a0 += __shfl_xor(a0, 16, 64);  a1 += __shfl_xor(a1, 16, 64);
    a2 += __shfl_xor(a2, 16, 64);  a3 += __shfl_xor(a3, 16, 64);
    a0 += __shfl_xor(a0, 32, 64);  a1 += __shfl_xor(a1, 32, 64);
    a2 += __shfl_xor(a2, 32, 64);  a3 += __shfl_xor(a3, 32, 64);
    if (lane < 16) {
        float4 o; o.x = a0; o.y = a1; o.z = a2; o.w = a3;
        *(float4*)(out + qbase + lane * 4) = o;
    }
}

// ---------------- fallback (R3, f32, no workspace) ----------------
__global__ __launch_bounds__(WPB * 64)
void wayfinder_attn_f32(const float* __restrict__ q,
                        const float* __restrict__ k,
                        const float* __restrict__ v,
                        const float* __restrict__ etb,
                        const int*   __restrict__ neigh_idx,
                        const int*   __restrict__ edge_type,
                        float*       __restrict__ out)
{
    __shared__ int   j_s[WPB][NB];
    __shared__ float w_s[WPB][NB];

    const int lane = threadIdx.x & 63;
    const int wave = threadIdx.x >> 6;
    const int wq   = blockIdx.x * WPB + wave;
    const int t    = wq & (T_DIM - 1);
    const long long qbase    = (long long)wq * DH;
    const long long headbase = (long long)(wq - t) * DH;

    const long long nbase = (long long)wq * NB;
    const int raw = neigh_idx[nbase + lane];
    const int et  = edge_type[nbase + lane];
    const bool valid = (raw >= 0) && (raw <= t);
    const int  sj   = min(max(raw, 0), T_DIM - 1);
    j_s[wave][lane] = sj;

    const int c = lane & 15;
    const int g = lane >> 4;
    const float4 qv = *(const float4*)(q + qbase + c * 4);

    int jarr[16];
    {
        const int4* jg = (const int4*)&j_s[wave][g * 16];
        *(int4*)&jarr[0]  = jg[0];
        *(int4*)&jarr[4]  = jg[1];
        *(int4*)&jarr[8]  = jg[2];
        *(int4*)&jarr[12] = jg[3];
    }

    const float* __restrict__ khead = k + headbase;
    float mydot = 0.f;
    #pragma unroll
    for (int i = 0; i < 16; ++i) {
        const float4 kv = *(const float4*)(khead + (long long)jarr[i] * DH + c * 4);
        float p = kv.x * qv.x + kv.y * qv.y + kv.z * qv.z + kv.w * qv.w;
        p += __shfl_xor(p, 1, 64);
        p += __shfl_xor(p, 2, 64);
        p += __shfl_xor(p, 4, 64);
        p += __shfl_xor(p, 8, 64);
        if (c == i) mydot = p;
    }

    const float bias  = (et != 0) ? etb[et - 1] : 0.f;
    const float score = valid ? (mydot * 0.125f + bias) : -INFINITY;

    float m = score;
    #pragma unroll
    for (int o = 32; o > 0; o >>= 1) m = fmaxf(m, __shfl_xor(m, o, 64));
    const float e = valid ? __expf(score - m) : 0.f;
    float s = e;
    #pragma unroll
    for (int o = 32; o > 0; o >>= 1) s += __shfl_xor(s, o, 64);
    const float w = e / fmaxf(s, 1e-20f);
    w_s[wave][lane] = w;

    const float* __restrict__ vhead = v + headbase;
    float acc = 0.f;
    #pragma unroll
    for (int d4 = 0; d4 < 16; ++d4) {
        const float4 wd = *(const float4*)&w_s[wave][d4 * 4];
        const int4   jd = *(const int4*)&j_s[wave][d4 * 4];
        acc += wd.x * vhead[(long long)jd.x * DH + lane];
        acc += wd.y * vhead[(long long)jd.y * DH + lane];
        acc += wd.z * vhead[(long long)jd.z * DH + lane];
        acc += wd.w * vhead[(long long)jd.w * DH + lane];
    }
    out[qbase + lane] = acc;
}

extern "C" void kernel_launch(void* const* d_in, const int* in_sizes, int n_in,
                              void* d_out, int out_size, void* d_ws, size_t ws_size,
                              hipStream_t stream)
{
    const float* q   = (const float*)d_in[0];
    const float* k   = (const float*)d_in[1];
    const float* v   = (const float*)d_in[2];
    const float* etb = (const float*)d_in[3];
    const int* neigh_idx = (const int*)d_in[4];
    const int* edge_type = (const int*)d_in[5];
    float* out = (float*)d_out;

    const int total_queries = 16 * T_DIM;     // 32768
    const int blocks = total_queries / WPB;   // 8192
    const size_t need = (size_t)KV_ELEMS * 2 * sizeof(unsigned short); // 8 MB

    if (ws_size >= need) {
        unsigned int* ws = (unsigned int*)d_ws;
        hipLaunchKernelGGL(convert_kv_kernel, dim3(KV_ELEMS / 4 / 256), dim3(256),
                           0, stream, k, v, ws);
        hipLaunchKernelGGL(wayfinder_attn_f16, dim3(blocks), dim3(WPB * 64),
                           0, stream, q, ws, etb, neigh_idx, edge_type, out);
    } else {
        hipLaunchKernelGGL(wayfinder_attn_f32, dim3(blocks), dim3(WPB * 64),
                           0, stream, q, k, v, etb, neigh_idx, edge_type, out);
    }
}